// Round 1
// baseline (1201.201 us; speedup 1.0000x reference)
//
#include <hip/hip_runtime.h>
#include <hip/hip_bf16.h>

#define N_NODES 100000
#define N_EDGES 3200000
#define D_FEAT  512
#define HIDDEN  16
#define NCLS    40

// ---------------------------------------------------------------- utilities
__global__ __launch_bounds__(256) void k_init_deg(float* __restrict__ deg) {
    int i = blockIdx.x * blockDim.x + threadIdx.x;
    if (i < N_NODES) deg[i] = 1.0f;   // self-loop weight
}

__global__ __launch_bounds__(256) void k_deg(const int* __restrict__ col,
                                             const float* __restrict__ w,
                                             float* __restrict__ deg) {
    int e = blockIdx.x * blockDim.x + threadIdx.x;
    if (e < N_EDGES) atomicAdd(&deg[col[e]], w[e]);
}

__global__ __launch_bounds__(256) void k_dinv(float* __restrict__ deg) {
    int i = blockIdx.x * blockDim.x + threadIdx.x;
    if (i < N_NODES) deg[i] = 1.0f / sqrtf(deg[i]);   // deg >= 1 always
}

// ------------------------------------------------------- GEMM1: h1 = x @ W1
// wave-per-row; lane owns k in {4L..4L+3} and {256+4L..256+4L+3}; W1 fragment
// in registers (128 VGPR, loaded once per wave); 17-shuffle butterfly reduce.
__global__ __launch_bounds__(256) void k_gemm1(const float* __restrict__ x,
                                               const float* __restrict__ W,
                                               float* __restrict__ h) {
    const int lane = threadIdx.x & 63;
    const int wave = (blockIdx.x * blockDim.x + threadIdx.x) >> 6;
    const int nw   = (gridDim.x * blockDim.x) >> 6;

    float wA[4][16], wB[4][16];
#pragma unroll
    for (int j = 0; j < 4; ++j)
#pragma unroll
        for (int c = 0; c < 16; ++c) {
            wA[j][c] = W[(4 * lane + j) * 16 + c];
            wB[j][c] = W[(256 + 4 * lane + j) * 16 + c];
        }

    for (int r = wave; r < N_NODES; r += nw) {
        const float4* xr = (const float4*)(x + (long long)r * D_FEAT);
        float4 xa = xr[lane];
        float4 xb = xr[lane + 64];
        float acc[16];
#pragma unroll
        for (int c = 0; c < 16; ++c)
            acc[c] = xa.x * wA[0][c] + xa.y * wA[1][c] + xa.z * wA[2][c] + xa.w * wA[3][c]
                   + xb.x * wB[0][c] + xb.y * wB[1][c] + xb.z * wB[2][c] + xb.w * wB[3][c];

        // halving butterfly: 16 -> 8 -> 4 -> 2 -> 1 values, then 2 plain steps
        float a8[8];
        {
            const bool up = lane & 1;
#pragma unroll
            for (int i = 0; i < 8; ++i) {
                float send = up ? acc[i] : acc[i + 8];
                float keep = up ? acc[i + 8] : acc[i];
                a8[i] = keep + __shfl_xor(send, 1, 64);
            }
        }
        float a4[4];
        {
            const bool up = lane & 2;
#pragma unroll
            for (int i = 0; i < 4; ++i) {
                float send = up ? a8[i] : a8[i + 4];
                float keep = up ? a8[i + 4] : a8[i];
                a4[i] = keep + __shfl_xor(send, 2, 64);
            }
        }
        float a2[2];
        {
            const bool up = lane & 4;
#pragma unroll
            for (int i = 0; i < 2; ++i) {
                float send = up ? a2[i] * 0.0f + a4[i] : a4[i + 2];  // see below
                (void)send;
            }
            // (written explicitly to avoid confusion)
            float s0 = up ? a4[0] : a4[2];
            float k0 = up ? a4[2] : a4[0];
            float s1 = up ? a4[1] : a4[3];
            float k1 = up ? a4[3] : a4[1];
            a2[0] = k0 + __shfl_xor(s0, 4, 64);
            a2[1] = k1 + __shfl_xor(s1, 4, 64);
        }
        float v;
        {
            const bool up = lane & 8;
            float send = up ? a2[0] : a2[1];
            float keep = up ? a2[1] : a2[0];
            v = keep + __shfl_xor(send, 8, 64);
        }
        v += __shfl_xor(v, 16, 64);
        v += __shfl_xor(v, 32, 64);

        if (lane < 16) {
            int c = ((lane & 1) << 3) | ((lane & 2) << 1) | ((lane & 4) >> 1) | ((lane & 8) >> 3);
            h[(long long)r * HIDDEN + c] = v;
        }
    }
}

// ------------------------------------------- layer-1 self-loop + bias init
__global__ __launch_bounds__(256) void k_self1(const float* __restrict__ h1,
                                               const float* __restrict__ dinv,
                                               const float* __restrict__ b,
                                               float* __restrict__ out1) {
    int idx = blockIdx.x * blockDim.x + threadIdx.x;
    if (idx < N_NODES * HIDDEN) {
        int i = idx >> 4, c = idx & 15;
        float d = dinv[i];
        out1[idx] = d * d * h1[idx] + b[c];
    }
}

// ----------------------------------------------------- layer-1 edge scatter
__global__ __launch_bounds__(256) void k_scat1(const int* __restrict__ row,
                                               const int* __restrict__ col,
                                               const float* __restrict__ w,
                                               const float* __restrict__ dinv,
                                               const float* __restrict__ h1,
                                               float* __restrict__ out1) {
    const int total = N_EDGES * HIDDEN;
    const int stride = gridDim.x * blockDim.x;
    for (int idx = blockIdx.x * blockDim.x + threadIdx.x; idx < total; idx += stride) {
        int e = idx >> 4, c = idx & 15;
        int r = row[e], t = col[e];
        float nrm = dinv[r] * w[e] * dinv[t];
        atomicAdd(&out1[t * HIDDEN + c], nrm * h1[r * HIDDEN + c]);
    }
}

// --------------------------------------- GEMM2: h2 = relu(out1) @ W2 (16x40)
__global__ __launch_bounds__(256) void k_gemm2(const float* __restrict__ out1,
                                               const float* __restrict__ W2,
                                               float* __restrict__ h2) {
    __shared__ float Ws[HIDDEN * NCLS];
    for (int i = threadIdx.x; i < HIDDEN * NCLS; i += blockDim.x) Ws[i] = W2[i];
    __syncthreads();
    const int total = N_NODES * NCLS;
    const int stride = gridDim.x * blockDim.x;
    for (int idx = blockIdx.x * blockDim.x + threadIdx.x; idx < total; idx += stride) {
        int i = idx / NCLS, c = idx - i * NCLS;
        const float* r = out1 + i * HIDDEN;
        float s = 0.0f;
#pragma unroll
        for (int k = 0; k < HIDDEN; ++k) {
            float v = r[k];
            v = v > 0.0f ? v : 0.0f;
            s += v * Ws[k * NCLS + c];
        }
        h2[idx] = s;
    }
}

// ------------------------------------------- layer-2 self-loop + bias init
__global__ __launch_bounds__(256) void k_self2(const float* __restrict__ h2,
                                               const float* __restrict__ dinv,
                                               const float* __restrict__ b,
                                               float* __restrict__ out) {
    const int total = N_NODES * NCLS;
    const int stride = gridDim.x * blockDim.x;
    for (int idx = blockIdx.x * blockDim.x + threadIdx.x; idx < total; idx += stride) {
        int i = idx / NCLS, c = idx - i * NCLS;
        float d = dinv[i];
        out[idx] = d * d * h2[idx] + b[c];
    }
}

// ----------------------------------------------------- layer-2 edge scatter
__global__ __launch_bounds__(256) void k_scat2(const int* __restrict__ row,
                                               const int* __restrict__ col,
                                               const float* __restrict__ w,
                                               const float* __restrict__ dinv,
                                               const float* __restrict__ h2,
                                               float* __restrict__ out) {
    const int total = N_EDGES * NCLS;   // 128,000,000 < 2^31
    const int stride = gridDim.x * blockDim.x;
    for (int idx = blockIdx.x * blockDim.x + threadIdx.x; idx < total; idx += stride) {
        int e = idx / NCLS, c = idx - e * NCLS;
        int r = row[e], t = col[e];
        float nrm = dinv[r] * w[e] * dinv[t];
        atomicAdd(&out[t * NCLS + c], nrm * h2[r * NCLS + c]);
    }
}

// --------------------------------------------------------------------- host
extern "C" void kernel_launch(void* const* d_in, const int* in_sizes, int n_in,
                              void* d_out, int out_size, void* d_ws, size_t ws_size,
                              hipStream_t stream) {
    const float* x   = (const float*)d_in[0];
    const int*   ei  = (const int*)d_in[1];
    const float* ew  = (const float*)d_in[2];
    const float* W1  = (const float*)d_in[3];
    const float* b1  = (const float*)d_in[4];
    const float* W2  = (const float*)d_in[5];
    const float* b2  = (const float*)d_in[6];
    const int* row = ei;
    const int* col = ei + N_EDGES;
    float* out = (float*)d_out;

    // workspace layout (33 MB total)
    char* ws = (char*)d_ws;
    float* dinv = (float*)(ws);                       // 400 KB (deg, then dinv in place)
    float* h1   = (float*)(ws + (1u << 20));          // 6.4 MB
    float* out1 = (float*)(ws + 9u * (1u << 20));     // 6.4 MB
    float* h2   = (float*)(ws + 17u * (1u << 20));    // 16 MB

    // 1. degree (init to 1.0 for self-loop) + dinv
    k_init_deg<<<(N_NODES + 255) / 256, 256, 0, stream>>>(dinv);
    k_deg<<<(N_EDGES + 255) / 256, 256, 0, stream>>>(col, ew, dinv);
    k_dinv<<<(N_NODES + 255) / 256, 256, 0, stream>>>(dinv);

    // 2. h1 = x @ W1
    k_gemm1<<<1024, 256, 0, stream>>>(x, W1, h1);

    // 3. layer-1 aggregation: self + bias, then edge scatter
    k_self1<<<(N_NODES * HIDDEN + 255) / 256, 256, 0, stream>>>(h1, dinv, b1, out1);
    k_scat1<<<4096, 256, 0, stream>>>(row, col, ew, dinv, h1, out1);

    // 4. h2 = relu(out1) @ W2
    k_gemm2<<<4096, 256, 0, stream>>>(out1, W2, h2);

    // 5. layer-2 aggregation into d_out
    k_self2<<<4096, 256, 0, stream>>>(h2, dinv, b2, out);
    k_scat2<<<8192, 256, 0, stream>>>(row, col, ew, dinv, h2, out);
}

// Round 5
// 1018.674 us; speedup vs baseline: 1.1792x; 1.1792x over previous
//
#include <hip/hip_runtime.h>
#include <hip/hip_bf16.h>

#define N_NODES 100000
#define N_EDGES 3200000
#define D_FEAT  512
#define HIDDEN  16
#define NCLS    40
#define SCAN_BLOCKS ((N_NODES + 255) / 256)   // 391

// ---------------------------------------------------------------- degree
__global__ __launch_bounds__(256) void k_init_deg(float* __restrict__ deg) {
    int i = blockIdx.x * blockDim.x + threadIdx.x;
    if (i < N_NODES) deg[i] = 1.0f;   // self-loop weight
}

__global__ __launch_bounds__(256) void k_deg(const int* __restrict__ col,
                                             const float* __restrict__ w,
                                             float* __restrict__ deg) {
    int e = blockIdx.x * blockDim.x + threadIdx.x;
    if (e < N_EDGES) atomicAdd(&deg[col[e]], w[e]);
}

__global__ __launch_bounds__(256) void k_dinv(float* __restrict__ deg) {
    int i = blockIdx.x * blockDim.x + threadIdx.x;
    if (i < N_NODES) deg[i] = 1.0f / sqrtf(deg[i]);   // deg >= 1 always
}

// ---------------------------------------------------------------- CSC build
__global__ __launch_bounds__(256) void k_zero_cnt(int* __restrict__ cnt) {
    int i = blockIdx.x * blockDim.x + threadIdx.x;
    if (i < N_NODES) cnt[i] = 0;
}

__global__ __launch_bounds__(256) void k_count(const int* __restrict__ col,
                                               int* __restrict__ cnt) {
    int e = blockIdx.x * blockDim.x + threadIdx.x;
    if (e < N_EDGES) atomicAdd(&cnt[col[e]], 1);
}

// per-block exclusive scan (Hillis-Steele in LDS) + block sums
__global__ __launch_bounds__(256) void k_scan1(const int* __restrict__ cnt,
                                               int* __restrict__ off,
                                               int* __restrict__ bsum) {
    __shared__ int s[256];
    int t = threadIdx.x;
    int i = blockIdx.x * 256 + t;
    int v = (i < N_NODES) ? cnt[i] : 0;
    s[t] = v;
    __syncthreads();
#pragma unroll
    for (int d = 1; d < 256; d <<= 1) {
        int x = (t >= d) ? s[t - d] : 0;
        __syncthreads();
        s[t] += x;
        __syncthreads();
    }
    if (i < N_NODES) off[i] = s[t] - v;   // exclusive
    if (t == 255) bsum[blockIdx.x] = s[255];
}

// serial exclusive scan of block sums (391 elements) + sentinel
__global__ void k_scan2(int* __restrict__ bsum, int* __restrict__ off) {
    if (threadIdx.x == 0 && blockIdx.x == 0) {
        int run = 0;
        for (int b = 0; b < SCAN_BLOCKS; ++b) {
            int v = bsum[b];
            bsum[b] = run;
            run += v;
        }
        off[N_NODES] = N_EDGES;
    }
}

__global__ __launch_bounds__(256) void k_scan3(int* __restrict__ off,
                                               const int* __restrict__ bsum,
                                               int* __restrict__ cursor) {
    int i = blockIdx.x * 256 + threadIdx.x;
    if (i < N_NODES) {
        int v = off[i] + bsum[blockIdx.x];
        off[i] = v;
        cursor[i] = v;
    }
}

// fill CSC: src[pos] = source node, val[pos] = full normalized edge weight
__global__ __launch_bounds__(256) void k_fill(const int* __restrict__ row,
                                              const int* __restrict__ col,
                                              const float* __restrict__ w,
                                              const float* __restrict__ dinv,
                                              int* __restrict__ cursor,
                                              int* __restrict__ src,
                                              float* __restrict__ val) {
    int e = blockIdx.x * blockDim.x + threadIdx.x;
    if (e < N_EDGES) {
        int r = row[e], t = col[e];
        int p = atomicAdd(&cursor[t], 1);
        src[p] = r;
        val[p] = dinv[r] * w[e] * dinv[t];
    }
}

// ------------------------------------------------------- GEMM1: h1 = x @ W1
// wave-per-row; lane owns k in {4L..4L+3} and {256+4L..256+4L+3}; W1 fragment
// in registers; halving-butterfly reduce (17 shuffles).
__global__ __launch_bounds__(256) void k_gemm1(const float* __restrict__ x,
                                               const float* __restrict__ W,
                                               float* __restrict__ h) {
    const int lane = threadIdx.x & 63;
    const int wave = (blockIdx.x * blockDim.x + threadIdx.x) >> 6;
    const int nw   = (gridDim.x * blockDim.x) >> 6;

    float wA[4][16], wB[4][16];
#pragma unroll
    for (int j = 0; j < 4; ++j)
#pragma unroll
        for (int c = 0; c < 16; ++c) {
            wA[j][c] = W[(4 * lane + j) * 16 + c];
            wB[j][c] = W[(256 + 4 * lane + j) * 16 + c];
        }

    for (int r = wave; r < N_NODES; r += nw) {
        const float4* xr = (const float4*)(x + (long long)r * D_FEAT);
        float4 xa = xr[lane];
        float4 xb = xr[lane + 64];
        float acc[16];
#pragma unroll
        for (int c = 0; c < 16; ++c)
            acc[c] = xa.x * wA[0][c] + xa.y * wA[1][c] + xa.z * wA[2][c] + xa.w * wA[3][c]
                   + xb.x * wB[0][c] + xb.y * wB[1][c] + xb.z * wB[2][c] + xb.w * wB[3][c];

        float a8[8];
        {
            const bool up = lane & 1;
#pragma unroll
            for (int i = 0; i < 8; ++i) {
                float send = up ? acc[i] : acc[i + 8];
                float keep = up ? acc[i + 8] : acc[i];
                a8[i] = keep + __shfl_xor(send, 1, 64);
            }
        }
        float a4[4];
        {
            const bool up = lane & 2;
#pragma unroll
            for (int i = 0; i < 4; ++i) {
                float send = up ? a8[i] : a8[i + 4];
                float keep = up ? a8[i + 4] : a8[i];
                a4[i] = keep + __shfl_xor(send, 2, 64);
            }
        }
        float a2[2];
        {
            const bool up = lane & 4;
            float s0 = up ? a4[0] : a4[2];
            float k0 = up ? a4[2] : a4[0];
            float s1 = up ? a4[1] : a4[3];
            float k1 = up ? a4[3] : a4[1];
            a2[0] = k0 + __shfl_xor(s0, 4, 64);
            a2[1] = k1 + __shfl_xor(s1, 4, 64);
        }
        float v;
        {
            const bool up = lane & 8;
            float send = up ? a2[0] : a2[1];
            float keep = up ? a2[1] : a2[0];
            v = keep + __shfl_xor(send, 8, 64);
        }
        v += __shfl_xor(v, 16, 64);
        v += __shfl_xor(v, 32, 64);

        if (lane < 16) {
            int c = ((lane & 1) << 3) | ((lane & 2) << 1) | ((lane & 4) >> 1) | ((lane & 8) >> 3);
            h[(long long)r * HIDDEN + c] = v;
        }
    }
}

// ------------------------------------------------------- CSC gather-aggregate
// wave per node: lanes (c = lane&15, j = lane>>4) process 4 edges/iter over
// 16 channels; fold j-groups with 2 shuffles; fuse self-loop + bias + relu.
__global__ __launch_bounds__(256) void k_gather(const int* __restrict__ off,
                                                const int* __restrict__ src,
                                                const float* __restrict__ val,
                                                const float* __restrict__ h,
                                                const float* __restrict__ dinv,
                                                const float* __restrict__ bias,
                                                float* __restrict__ out,
                                                int relu_out) {
    const int lane = threadIdx.x & 63;
    const int c = lane & 15, j = lane >> 4;
    const int wave = (blockIdx.x * blockDim.x + threadIdx.x) >> 6;
    const int nw   = (gridDim.x * blockDim.x) >> 6;

    for (int t = wave; t < N_NODES; t += nw) {
        const int s0 = off[t], s1 = off[t + 1];
        float acc = 0.0f;
        for (int p = s0 + j; p < s1; p += 4) {
            int r = src[p];
            float nv = val[p];
            acc += nv * h[r * HIDDEN + c];
        }
        acc += __shfl_xor(acc, 16, 64);
        acc += __shfl_xor(acc, 32, 64);
        if (lane < 16) {
            float d = dinv[t];
            float v = acc + d * d * h[t * HIDDEN + c];
            if (bias) v += bias[c];
            if (relu_out) v = v > 0.0f ? v : 0.0f;
            out[t * HIDDEN + c] = v;
        }
    }
}

// --------------------------------- GEMM2 + bias: out = agg2 @ W2 + b2 (16x40)
__global__ __launch_bounds__(256) void k_gemm2(const float* __restrict__ agg,
                                               const float* __restrict__ W2,
                                               const float* __restrict__ b2,
                                               float* __restrict__ out) {
    __shared__ float Ws[HIDDEN * NCLS];
    for (int i = threadIdx.x; i < HIDDEN * NCLS; i += blockDim.x) Ws[i] = W2[i];
    __syncthreads();
    int idx = blockIdx.x * blockDim.x + threadIdx.x;
    if (idx < N_NODES * NCLS) {
        int i = idx / NCLS, c = idx - i * NCLS;
        const float* r = agg + i * HIDDEN;
        float s = b2[c];
#pragma unroll
        for (int k = 0; k < HIDDEN; ++k) s += r[k] * Ws[k * NCLS + c];
        out[idx] = s;
    }
}

// --------------------------------------------------------------------- host
extern "C" void kernel_launch(void* const* d_in, const int* in_sizes, int n_in,
                              void* d_out, int out_size, void* d_ws, size_t ws_size,
                              hipStream_t stream) {
    const float* x   = (const float*)d_in[0];
    const int*   ei  = (const int*)d_in[1];
    const float* ew  = (const float*)d_in[2];
    const float* W1  = (const float*)d_in[3];
    const float* b1  = (const float*)d_in[4];
    const float* W2  = (const float*)d_in[5];
    const float* b2  = (const float*)d_in[6];
    const int* row = ei;
    const int* col = ei + N_EDGES;
    float* out = (float*)d_out;

    // workspace layout (~40 MB); cursor reuses cnt, agg2 reuses h1
    char* ws = (char*)d_ws;
    float* dinv   = (float*)(ws);                      // 400 KB  @ 0
    int*   cnt    = (int*)  (ws +  1u * (1u << 19));   // 400 KB  @ 0.5M (also cursor)
    int*   off    = (int*)  (ws +  2u * (1u << 19));   // 400 KB+4@ 1.0M
    int*   bsum   = (int*)  (ws +  3u * (1u << 19));   // 1.6 KB  @ 1.5M
    int*   src    = (int*)  (ws +  2u * (1u << 20));   // 12.8 MB @ 2M
    float* val    = (float*)(ws + 15u * (1u << 20));   // 12.8 MB @ 15M
    float* h1     = (float*)(ws + 28u * (1u << 20));   //  6.4 MB @ 28M (also agg2)
    float* hrelu  = (float*)(ws + 35u * (1u << 20));   //  6.4 MB @ 35M
    int*   cursor = cnt;     // cnt dead after k_scan1
    float* agg2   = h1;      // h1 dead after layer-1 gather

    const int EB = (N_EDGES + 255) / 256;   // 12500

    // 1. degree (self-loop = 1.0) -> dinv
    k_init_deg<<<SCAN_BLOCKS, 256, 0, stream>>>(dinv);
    k_deg<<<EB, 256, 0, stream>>>(col, ew, dinv);
    k_dinv<<<SCAN_BLOCKS, 256, 0, stream>>>(dinv);

    // 2. CSC build (shared by both layers)
    k_zero_cnt<<<SCAN_BLOCKS, 256, 0, stream>>>(cnt);
    k_count<<<EB, 256, 0, stream>>>(col, cnt);
    k_scan1<<<SCAN_BLOCKS, 256, 0, stream>>>(cnt, off, bsum);
    k_scan2<<<1, 64, 0, stream>>>(bsum, off);
    k_scan3<<<SCAN_BLOCKS, 256, 0, stream>>>(off, bsum, cursor);
    k_fill<<<EB, 256, 0, stream>>>(row, col, ew, dinv, cursor, src, val);

    // 3. h1 = x @ W1
    k_gemm1<<<1024, 256, 0, stream>>>(x, W1, h1);

    // 4. layer-1 aggregate (+b1, relu) -> hrelu
    k_gather<<<2048, 256, 0, stream>>>(off, src, val, h1, dinv, b1, hrelu, 1);

    // 5. layer-2 aggregate (16-wide, pre-W2; reassociated GCN2) -> agg2
    k_gather<<<2048, 256, 0, stream>>>(off, src, val, hrelu, dinv, nullptr, agg2, 0);

    // 6. out = agg2 @ W2 + b2
    k_gemm2<<<(N_NODES * NCLS + 255) / 256, 256, 0, stream>>>(agg2, W2, b2, out);
}